// Round 3
// baseline (225.544 us; speedup 1.0000x reference)
//
#include <hip/hip_runtime.h>
#include <hip/hip_bf16.h>
#include <stdint.h>

// Problem constants (B=16384, F=2048, K=64), fp32 inputs/outputs.
#define F_DIM 2048
#define K_DIM 64

typedef float  floatx4 __attribute__((ext_vector_type(4)));
typedef short  short8  __attribute__((ext_vector_type(8)));

__device__ __forceinline__ short f32_to_bf16_rne(float f) {
    unsigned int u = __builtin_bit_cast(unsigned int, f);
    u += 0x7fffu + ((u >> 16) & 1u);            // round-to-nearest-even
    return (short)(u >> 16);
}

// Prep: (a) pack v (2048x64 fp32) into bf16 MFMA B-fragment layout:
//   frag id = c*4 + t (c = f-chunk of 32, t = n-tile of 16), lane l holds
//   B[k = c*32 + (l>>4)*8 + j][n = t*16 + (l&15)], j=0..7 contiguous.
//   short8 index = c*256 + t*64 + l.
// (b) s[f] = sum_k v[f][k]^2 in fp32 (exact second term).
__global__ __launch_bounds__(256) void fm_prep(const float* __restrict__ v,
                                               short* __restrict__ vp,
                                               float* __restrict__ s) {
    const int bid = blockIdx.x;
    const int tid = threadIdx.x;
    if (bid < 64) {
        const int gid    = bid * 256 + tid;   // 0..16383 fragment-threads
        const int fragid = gid >> 6;          // c*4 + t
        const int l      = gid & 63;
        const int c      = fragid >> 2;
        const int t      = fragid & 3;
        const int fbase  = c * 32 + (l >> 4) * 8;
        const int n      = t * 16 + (l & 15);
        short8 frag;
#pragma unroll
        for (int j = 0; j < 8; ++j)
            frag[j] = f32_to_bf16_rne(v[(size_t)(fbase + j) * K_DIM + n]);
        *reinterpret_cast<short8*>(vp + (size_t)gid * 8) = frag;
    } else {
        const int f = (bid - 64) * 256 + tid; // 0..2047
        const float4* vr = reinterpret_cast<const float4*>(v + (size_t)f * K_DIM);
        float acc = 0.f;
#pragma unroll
        for (int i = 0; i < 16; ++i) {
            float4 q = vr[i];
            acc += q.x * q.x + q.y * q.y + q.z * q.z + q.w * q.w;
        }
        s[f] = acc;
    }
}

// Main v3: block = 256 threads = 4 waves, one 16-row tile per block.
// Wave w covers F-quarter [w*512,(w+1)*512) as 16 chunks of 32 features.
// Low register pressure: only 4 B-frags live; A/s prefetched distance-2.
__global__ __launch_bounds__(256, 4) void fm_main(const float* __restrict__ x,
                                                  const short* __restrict__ vp,
                                                  const float* __restrict__ s,
                                                  float* __restrict__ out) {
    const int t = threadIdx.x;
    const int w = t >> 6;      // wave id (F-quarter)
    const int l = t & 63;
    const int r = l & 15;      // row within tile (A), col within n-tile (B/D)
    const int g = l >> 4;      // k-group / D row-group
    const int row_base = blockIdx.x * 16;
    const int f0 = w * 512;

    const float*  xp = x + (size_t)(row_base + r) * F_DIM + f0 + g * 8;
    const float*  sp = s + f0 + g * 8;
    const short8* bp = reinterpret_cast<const short8*>(vp) + (size_t)(w * 16) * 256 + l;

    floatx4 acc0 = {0.f, 0.f, 0.f, 0.f};
    floatx4 acc1 = acc0, acc2 = acc0, acc3 = acc0;
    float x2s = 0.f;

    // Rotating prefetch buffers: cur (a0,a1/s0,s1), next (na*/ns*)
    float4 a0  = *(const float4*)(xp);
    float4 a1  = *(const float4*)(xp + 4);
    float4 na0 = *(const float4*)(xp + 32);
    float4 na1 = *(const float4*)(xp + 36);
    float4 s0  = *(const float4*)(sp);
    float4 s1  = *(const float4*)(sp + 4);
    float4 ns0 = *(const float4*)(sp + 32);
    float4 ns1 = *(const float4*)(sp + 36);

#pragma unroll
    for (int c = 0; c < 16; ++c) {
        // B fragments for this chunk (L2-resident; used ~90 VALU-cycles later)
        short8 b0 = bp[0];
        short8 b1 = bp[64];
        short8 b2 = bp[128];
        short8 b3 = bp[192];
        bp += 256;

        // Distance-2 prefetch of A and s
        float4 pa0 = {0.f,0.f,0.f,0.f}, pa1 = pa0, ps0 = pa0, ps1 = pa0;
        if (c + 2 < 16) {
            const float* nx = xp + (c + 2) * 32;
            const float* ns = sp + (c + 2) * 32;
            pa0 = *(const float4*)(nx);
            pa1 = *(const float4*)(nx + 4);
            ps0 = *(const float4*)(ns);
            ps1 = *(const float4*)(ns + 4);
        }

        // Convert A to bf16 fragment (k = g*8 + j, j contiguous)
        short8 af;
        af[0] = f32_to_bf16_rne(a0.x); af[1] = f32_to_bf16_rne(a0.y);
        af[2] = f32_to_bf16_rne(a0.z); af[3] = f32_to_bf16_rne(a0.w);
        af[4] = f32_to_bf16_rne(a1.x); af[5] = f32_to_bf16_rne(a1.y);
        af[6] = f32_to_bf16_rne(a1.z); af[7] = f32_to_bf16_rne(a1.w);

        // Exact fp32 second term: sum_f x_f^2 * s_f (partial per lane)
        x2s = fmaf(a0.x * a0.x, s0.x, x2s);
        x2s = fmaf(a0.y * a0.y, s0.y, x2s);
        x2s = fmaf(a0.z * a0.z, s0.z, x2s);
        x2s = fmaf(a0.w * a0.w, s0.w, x2s);
        x2s = fmaf(a1.x * a1.x, s1.x, x2s);
        x2s = fmaf(a1.y * a1.y, s1.y, x2s);
        x2s = fmaf(a1.z * a1.z, s1.z, x2s);
        x2s = fmaf(a1.w * a1.w, s1.w, x2s);

        acc0 = __builtin_amdgcn_mfma_f32_16x16x32_bf16(af, b0, acc0, 0, 0, 0);
        acc1 = __builtin_amdgcn_mfma_f32_16x16x32_bf16(af, b1, acc1, 0, 0, 0);
        acc2 = __builtin_amdgcn_mfma_f32_16x16x32_bf16(af, b2, acc2, 0, 0, 0);
        acc3 = __builtin_amdgcn_mfma_f32_16x16x32_bf16(af, b3, acc3, 0, 0, 0);

        // Rotate buffers
        a0 = na0; a1 = na1; s0 = ns0; s1 = ns1;
        na0 = pa0; na1 = pa1; ns0 = ps0; ns1 = ps1;
    }

    // ---- Cross-wave reduction of partial xv, then square-reduce ----
    // D layout: n = t*16 + (l&15), m = g*4 + reg. red[w][l][t*4+reg], pad 17.
    __shared__ float red[4][64][17];   // 17.4 KB
    __shared__ float x2r[4][16];
    __shared__ float lds_sq[16];

#pragma unroll
    for (int j = 0; j < 4; ++j) {
        red[w][l][j]      = acc0[j];
        red[w][l][4 + j]  = acc1[j];
        red[w][l][8 + j]  = acc2[j];
        red[w][l][12 + j] = acc3[j];
    }
    // x2s partials: per (row=r, group=g); reduce over g (high 2 lane bits)
    x2s += __shfl_xor(x2s, 16, 64);
    x2s += __shfl_xor(x2s, 32, 64);
    if (g == 0) x2r[w][r] = x2s;
    __syncthreads();

    if (w == 0) {
        float vsum[16];
#pragma unroll
        for (int j = 0; j < 16; ++j)
            vsum[j] = red[0][l][j] + red[1][l][j] + red[2][l][j] + red[3][l][j];
        // sq_reg = sum over n-tiles of xv[m=g*4+reg][n]^2 (this lane's 4 n's)
        float sq0 = vsum[0]*vsum[0] + vsum[4]*vsum[4] + vsum[8]*vsum[8]  + vsum[12]*vsum[12];
        float sq1 = vsum[1]*vsum[1] + vsum[5]*vsum[5] + vsum[9]*vsum[9]  + vsum[13]*vsum[13];
        float sq2 = vsum[2]*vsum[2] + vsum[6]*vsum[6] + vsum[10]*vsum[10] + vsum[14]*vsum[14];
        float sq3 = vsum[3]*vsum[3] + vsum[7]*vsum[7] + vsum[11]*vsum[11] + vsum[15]*vsum[15];
#pragma unroll
        for (int off = 1; off < 16; off <<= 1) {
            sq0 += __shfl_xor(sq0, off, 64);
            sq1 += __shfl_xor(sq1, off, 64);
            sq2 += __shfl_xor(sq2, off, 64);
            sq3 += __shfl_xor(sq3, off, 64);
        }
        if (r == 0) {
            lds_sq[g * 4 + 0] = sq0;
            lds_sq[g * 4 + 1] = sq1;
            lds_sq[g * 4 + 2] = sq2;
            lds_sq[g * 4 + 3] = sq3;
        }
    }
    __syncthreads();
    if (t < 16) {
        float x2full = x2r[0][t] + x2r[1][t] + x2r[2][t] + x2r[3][t];
        out[row_base + t] = 0.5f * (lds_sq[t] - x2full);
    }
}

extern "C" void kernel_launch(void* const* d_in, const int* in_sizes, int n_in,
                              void* d_out, int out_size, void* d_ws, size_t ws_size,
                              hipStream_t stream) {
    const float* x = (const float*)d_in[0];   // (16384, 2048) fp32
    const float* v = (const float*)d_in[1];   // (2048, 64) fp32
    float* out = (float*)d_out;               // (16384,) fp32

    short* vp = (short*)d_ws;                               // 262144 B packed bf16 B-frags
    float* s  = (float*)((char*)d_ws + (size_t)16384 * 16); // 8192 B: s[f]

    fm_prep<<<72, 256, 0, stream>>>(v, vp, s);
    // PROBE: fm_main launched TWICE (idempotent — writes identical out).
    // dur_us - 202 reads off fm_main's standalone cost, which the top-5
    // rocprof cutoff (77-us harness fills) has hidden for two rounds.
    fm_main<<<16384 / 16, 256, 0, stream>>>(x, vp, s, out);
    fm_main<<<16384 / 16, 256, 0, stream>>>(x, vp, s, out);
}

// Round 4
// 197.940 us; speedup vs baseline: 1.1395x; 1.1395x over previous
//
#include <hip/hip_runtime.h>
#include <hip/hip_bf16.h>
#include <stdint.h>

// Problem constants (B=16384, F=2048, K=64), fp32 inputs/outputs.
#define F_DIM 2048
#define K_DIM 64

typedef float  floatx4 __attribute__((ext_vector_type(4)));
typedef short  short8  __attribute__((ext_vector_type(8)));

__device__ __forceinline__ short f32_to_bf16_rne(float f) {
    unsigned int u = __builtin_bit_cast(unsigned int, f);
    u += 0x7fffu + ((u >> 16) & 1u);            // round-to-nearest-even
    return (short)(u >> 16);
}

// Prep: (a) pack v (2048x64 fp32) into bf16 MFMA B-fragment layout:
//   frag id = c*4 + t (c = f-chunk of 32, t = n-tile of 16), lane l holds
//   B[k = c*32 + (l>>4)*8 + j][n = t*16 + (l&15)], j=0..7 contiguous.
//   short8 index = c*256 + t*64 + l.
// (b) s[f] = sum_k v[f][k]^2 in fp32 (exact second term).
__global__ __launch_bounds__(256) void fm_prep(const float* __restrict__ v,
                                               short* __restrict__ vp,
                                               float* __restrict__ s) {
    const int bid = blockIdx.x;
    const int tid = threadIdx.x;
    if (bid < 64) {
        const int gid    = bid * 256 + tid;   // 0..16383 fragment-threads
        const int fragid = gid >> 6;          // c*4 + t
        const int l      = gid & 63;
        const int c      = fragid >> 2;
        const int t      = fragid & 3;
        const int fbase  = c * 32 + (l >> 4) * 8;
        const int n      = t * 16 + (l & 15);
        short8 frag;
#pragma unroll
        for (int j = 0; j < 8; ++j)
            frag[j] = f32_to_bf16_rne(v[(size_t)(fbase + j) * K_DIM + n]);
        *reinterpret_cast<short8*>(vp + (size_t)gid * 8) = frag;
    } else {
        const int f = (bid - 64) * 256 + tid; // 0..2047
        const float4* vr = reinterpret_cast<const float4*>(v + (size_t)f * K_DIM);
        float acc = 0.f;
#pragma unroll
        for (int i = 0; i < 16; ++i) {
            float4 q = vr[i];
            acc += q.x * q.x + q.y * q.y + q.z * q.z + q.w * q.w;
        }
        s[f] = acc;
    }
}

// Main: block = 256 threads = 4 waves, one 16-row tile per block.
// Wave w covers F-quarter [w*512,(w+1)*512) as 16 chunks of 32 features.
// Low register pressure: only 4 B-frags live; A/s prefetched distance-2.
// Measured (R3 double-launch probe): ~23.4 us/launch = ~92% of the 21.3 us
// HBM floor for the 134 MB x read. Memory-roofline-bound.
__global__ __launch_bounds__(256, 4) void fm_main(const float* __restrict__ x,
                                                  const short* __restrict__ vp,
                                                  const float* __restrict__ s,
                                                  float* __restrict__ out) {
    const int t = threadIdx.x;
    const int w = t >> 6;      // wave id (F-quarter)
    const int l = t & 63;
    const int r = l & 15;      // row within tile (A), col within n-tile (B/D)
    const int g = l >> 4;      // k-group / D row-group
    const int row_base = blockIdx.x * 16;
    const int f0 = w * 512;

    const float*  xp = x + (size_t)(row_base + r) * F_DIM + f0 + g * 8;
    const float*  sp = s + f0 + g * 8;
    const short8* bp = reinterpret_cast<const short8*>(vp) + (size_t)(w * 16) * 256 + l;

    floatx4 acc0 = {0.f, 0.f, 0.f, 0.f};
    floatx4 acc1 = acc0, acc2 = acc0, acc3 = acc0;
    float x2s = 0.f;

    // Rotating prefetch buffers: cur (a0,a1/s0,s1), next (na*/ns*)
    float4 a0  = *(const float4*)(xp);
    float4 a1  = *(const float4*)(xp + 4);
    float4 na0 = *(const float4*)(xp + 32);
    float4 na1 = *(const float4*)(xp + 36);
    float4 s0  = *(const float4*)(sp);
    float4 s1  = *(const float4*)(sp + 4);
    float4 ns0 = *(const float4*)(sp + 32);
    float4 ns1 = *(const float4*)(sp + 36);

#pragma unroll
    for (int c = 0; c < 16; ++c) {
        // B fragments for this chunk (L2-resident; used ~90 VALU-cycles later)
        short8 b0 = bp[0];
        short8 b1 = bp[64];
        short8 b2 = bp[128];
        short8 b3 = bp[192];
        bp += 256;

        // Distance-2 prefetch of A and s
        float4 pa0 = {0.f,0.f,0.f,0.f}, pa1 = pa0, ps0 = pa0, ps1 = pa0;
        if (c + 2 < 16) {
            const float* nx = xp + (c + 2) * 32;
            const float* ns = sp + (c + 2) * 32;
            pa0 = *(const float4*)(nx);
            pa1 = *(const float4*)(nx + 4);
            ps0 = *(const float4*)(ns);
            ps1 = *(const float4*)(ns + 4);
        }

        // Convert A to bf16 fragment (k = g*8 + j, j contiguous)
        short8 af;
        af[0] = f32_to_bf16_rne(a0.x); af[1] = f32_to_bf16_rne(a0.y);
        af[2] = f32_to_bf16_rne(a0.z); af[3] = f32_to_bf16_rne(a0.w);
        af[4] = f32_to_bf16_rne(a1.x); af[5] = f32_to_bf16_rne(a1.y);
        af[6] = f32_to_bf16_rne(a1.z); af[7] = f32_to_bf16_rne(a1.w);

        // Exact fp32 second term: sum_f x_f^2 * s_f (partial per lane)
        x2s = fmaf(a0.x * a0.x, s0.x, x2s);
        x2s = fmaf(a0.y * a0.y, s0.y, x2s);
        x2s = fmaf(a0.z * a0.z, s0.z, x2s);
        x2s = fmaf(a0.w * a0.w, s0.w, x2s);
        x2s = fmaf(a1.x * a1.x, s1.x, x2s);
        x2s = fmaf(a1.y * a1.y, s1.y, x2s);
        x2s = fmaf(a1.z * a1.z, s1.z, x2s);
        x2s = fmaf(a1.w * a1.w, s1.w, x2s);

        acc0 = __builtin_amdgcn_mfma_f32_16x16x32_bf16(af, b0, acc0, 0, 0, 0);
        acc1 = __builtin_amdgcn_mfma_f32_16x16x32_bf16(af, b1, acc1, 0, 0, 0);
        acc2 = __builtin_amdgcn_mfma_f32_16x16x32_bf16(af, b2, acc2, 0, 0, 0);
        acc3 = __builtin_amdgcn_mfma_f32_16x16x32_bf16(af, b3, acc3, 0, 0, 0);

        // Rotate buffers
        a0 = na0; a1 = na1; s0 = ns0; s1 = ns1;
        na0 = pa0; na1 = pa1; ns0 = ps0; ns1 = ps1;
    }

    // ---- Cross-wave reduction of partial xv, then square-reduce ----
    // D layout: n = t*16 + (l&15), m = g*4 + reg. red[w][l][t*4+reg], pad 17.
    __shared__ float red[4][64][17];   // 17.4 KB
    __shared__ float x2r[4][16];
    __shared__ float lds_sq[16];

#pragma unroll
    for (int j = 0; j < 4; ++j) {
        red[w][l][j]      = acc0[j];
        red[w][l][4 + j]  = acc1[j];
        red[w][l][8 + j]  = acc2[j];
        red[w][l][12 + j] = acc3[j];
    }
    // x2s partials: per (row=r, group=g); reduce over g (high 2 lane bits)
    x2s += __shfl_xor(x2s, 16, 64);
    x2s += __shfl_xor(x2s, 32, 64);
    if (g == 0) x2r[w][r] = x2s;
    __syncthreads();

    if (w == 0) {
        float vsum[16];
#pragma unroll
        for (int j = 0; j < 16; ++j)
            vsum[j] = red[0][l][j] + red[1][l][j] + red[2][l][j] + red[3][l][j];
        // sq_reg = sum over n-tiles of xv[m=g*4+reg][n]^2 (this lane's 4 n's)
        float sq0 = vsum[0]*vsum[0] + vsum[4]*vsum[4] + vsum[8]*vsum[8]  + vsum[12]*vsum[12];
        float sq1 = vsum[1]*vsum[1] + vsum[5]*vsum[5] + vsum[9]*vsum[9]  + vsum[13]*vsum[13];
        float sq2 = vsum[2]*vsum[2] + vsum[6]*vsum[6] + vsum[10]*vsum[10] + vsum[14]*vsum[14];
        float sq3 = vsum[3]*vsum[3] + vsum[7]*vsum[7] + vsum[11]*vsum[11] + vsum[15]*vsum[15];
#pragma unroll
        for (int off = 1; off < 16; off <<= 1) {
            sq0 += __shfl_xor(sq0, off, 64);
            sq1 += __shfl_xor(sq1, off, 64);
            sq2 += __shfl_xor(sq2, off, 64);
            sq3 += __shfl_xor(sq3, off, 64);
        }
        if (r == 0) {
            lds_sq[g * 4 + 0] = sq0;
            lds_sq[g * 4 + 1] = sq1;
            lds_sq[g * 4 + 2] = sq2;
            lds_sq[g * 4 + 3] = sq3;
        }
    }
    __syncthreads();
    if (t < 16) {
        float x2full = x2r[0][t] + x2r[1][t] + x2r[2][t] + x2r[3][t];
        out[row_base + t] = 0.5f * (lds_sq[t] - x2full);
    }
}

extern "C" void kernel_launch(void* const* d_in, const int* in_sizes, int n_in,
                              void* d_out, int out_size, void* d_ws, size_t ws_size,
                              hipStream_t stream) {
    const float* x = (const float*)d_in[0];   // (16384, 2048) fp32
    const float* v = (const float*)d_in[1];   // (2048, 64) fp32
    float* out = (float*)d_out;               // (16384,) fp32

    short* vp = (short*)d_ws;                               // 262144 B packed bf16 B-frags
    float* s  = (float*)((char*)d_ws + (size_t)16384 * 16); // 8192 B: s[f]

    fm_prep<<<72, 256, 0, stream>>>(v, vp, s);
    fm_main<<<16384 / 16, 256, 0, stream>>>(x, vp, s, out);
}